// Round 8
// baseline (169.215 us; speedup 1.0000x reference)
//
#include <hip/hip_runtime.h>
#include <math.h>

#define B_ROWS   1024
#define DIM      192
#define NCLS     100000
#define S_SCALE  30.0f
#define COS_M    0.98006657784124163f
#define SIN_M    0.19866933079506122f
#define TH_C     (-0.98006657784124163f)
#define MM_C     0.039733866159012243f
#define L2E30    43.2808512266689f      // 30 * log2(e)
#define EXPM30   9.357622968840175e-14f // exp(-30) = 2^-L2E30
#define LN2_C    0.69314718055994531f

// ---- old-path constants (kept as fallback when workspace is small) ----
#define NTILE_B  784
#define NCHUNKR  16
#define ASEG_CH  1536
#define NSLOT    1568

// ---- new-path constants ----
#define NCHUNKC  1568     // 64-class chunks total (1568*64 = 100352)
#define CSPLIT   128
#define NSLOT2   256      // 2 partial slots (cg) per cs
#define PACK_WGRID 3136
#define PACK_GRID  3168

typedef float floatx4 __attribute__((ext_vector_type(4)));
typedef __bf16 bf16x8 __attribute__((ext_vector_type(8)));

#define AS1 __attribute__((address_space(1)))
#define AS3 __attribute__((address_space(3)))

__device__ __forceinline__ unsigned int f2bf(float x) {
    unsigned int u = __float_as_uint(x);
    u = (u + 0x7fffu + ((u >> 16) & 1u)) >> 16;   // RNE
    return u;
}
__device__ __forceinline__ unsigned int pack2(float lo, float hi) {
    return f2bf(lo) | (f2bf(hi) << 16);
}
__device__ __forceinline__ float fexp2(float x) {
#if __has_builtin(__builtin_amdgcn_exp2f)
    return __builtin_amdgcn_exp2f(x);
#else
    float r; __asm__("v_exp_f32 %0, %1" : "=v"(r) : "v"(x)); return r;
#endif
}
template <int N>
__device__ __forceinline__ float ror16(float x) {
    return __int_as_float(__builtin_amdgcn_mov_dpp(
        __float_as_int(x), 0x120 | N, 0xF, 0xF, false));
}
// async global->LDS DMA, 16B/lane: wave-uniform LDS base + per-lane global
// src; direct addrspacecasts (R7-verified safe & fast).
__device__ __forceinline__ void gload_lds16(const void* g, void* l) {
    __builtin_amdgcn_global_load_lds(
        (const AS1 unsigned int*)g, (AS3 unsigned int*)l, 16, 0, 0);
}

// ===========================================================================
// NEW PATH
// ===========================================================================

// ---------------------------------------------------------------------------
// pack2 (R6/R7-verified): normalize + bf16 pack + MFMA-order swizzle,
// coalesced 512B stores via LDS transpose, XCD-aligned block permutation
// (chunk cc written on XCD cs(cc)%8 = reader's XCD). x-side bakes L2E30.
// ---------------------------------------------------------------------------
__global__ __launch_bounds__(256)
void pack2_kernel(const float* __restrict__ x, const float* __restrict__ w,
                  unsigned short* __restrict__ asw, unsigned short* __restrict__ wsw,
                  float* __restrict__ accum)
{
    __shared__ uint4 lds_pk[32][25];     // +1 pad: break phase-2 bank aliasing
    const int bid = blockIdx.x;
    const int t = threadIdx.x;
    const int r = t >> 3, oct = t & 7;

    const float* src;
    unsigned short* dstc;                // chunk base in destination
    int rowbase, half;
    bool wside;
    if (bid < PACK_WGRID) {
        // XCD class k = bid&7 owns all (cc,half) with cs(cc)%8 == k.
        const int k = bid & 7, j = bid >> 3;   // j in [0,392)
        int cs, cc, h;
        if (j < 104) {                   // cs < 32: 13 chunks x 2 halves = 26
            const int i = j / 26; h = j % 26;
            cs = k + 8 * i;  cc = cs * 13 + (h >> 1);
        } else {                         // cs >= 32: 12 chunks x 2 halves = 24
            const int j2 = j - 104;
            const int i = 4 + j2 / 24; h = j2 % 24;
            cs = k + 8 * i;  cc = 416 + (cs - 32) * 12 + (h >> 1);
        }
        half = h & 1;
        rowbase = cc * 64 + half * 32;
        src = w;  dstc = wsw + (size_t)cc * 12288;  wside = true;
    } else {
        const int xb = bid - PACK_WGRID;            // 0..31
        half = xb & 1;
        rowbase = xb * 32;
        src = x;  dstc = asw + (size_t)(xb >> 1) * 12288;  wside = false;
        if (bid == PACK_WGRID && t < 4) accum[t] = 0.0f;
    }

    const int row = rowbase + r;
    const bool live = !wside || (row < NCLS);
    float4 buf[6];
    float s = 0.f;
    if (live) {
        const float4* sp = (const float4*)(src + (size_t)row * DIM) + oct * 6;
        #pragma unroll
        for (int q = 0; q < 6; ++q) {
            float4 v = sp[q];
            buf[q] = v;
            s += v.x * v.x + v.y * v.y + v.z * v.z + v.w * v.w;
        }
    } else {
        #pragma unroll
        for (int q = 0; q < 6; ++q) buf[q] = make_float4(0.f, 0.f, 0.f, 0.f);
    }
    s += __shfl_xor(s, 1);
    s += __shfl_xor(s, 2);
    s += __shfl_xor(s, 4);
    float inv = live ? (1.0f / fmaxf(sqrtf(s), 1e-12f)) : 0.0f;
    if (!wside) inv *= L2E30;            // bake 30*log2(e) into x-side

    #pragma unroll
    for (int j = 0; j < 3; ++j) {
        const int k8 = oct * 3 + j;
        uint4 o;
        float4 a0 = buf[2 * j], a1 = buf[2 * j + 1];
        o.x = pack2(a0.x * inv, a0.y * inv);
        o.y = pack2(a0.z * inv, a0.w * inv);
        o.z = pack2(a1.x * inv, a1.y * inv);
        o.w = pack2(a1.z * inv, a1.w * inv);
        lds_pk[r][k8] = o;
    }
    __syncthreads();
    // coalesced store: 32 consecutive lanes write 32 consecutive 16B blocks
    #pragma unroll
    for (int j = 0; j < 3; ++j) {
        const int flat = j * 256 + t;                // [0,768)
        const int sseg = flat >> 5, rr = flat & 31;  // seg 0..23, row 0..31
        *(uint4*)(dstc + ((size_t)(sseg * 64) + half * 32 + rr) * 8)
            = lds_pk[rr][sseg];
    }
}

// ---------------------------------------------------------------------------
// gemm_stats9: 32x32 WAVE TILE for occupancy. R7 post-mortem: every M=64
// variant (96-VGPR A-set -> 2 waves/SIMD) walls at ~45 us vs the 19 us
// matrix floor — lockstep-phase TLP starvation, not bandwidth. Now each
// wave owns 32 rows (2 A-sets, 48 VGPR) x 32 classes (cg half of chunk):
// ~110 VGPR total, __launch_bounds__(256,4) caps at 128 -> 4 waves/SIMD
// VGPR-wise; 48KB LDS dbuf caps residency at 3 blocks/CU = 12 waves/CU
// (+50% TLP), with 3 independent chunk streams staggering phases. Block =
// 4 waves (2 rg x 2 cg) covering 64 rows x full chunk. Grid 16 rb x 128
// cs = 2048 (bid&127=cs keeps XCD mapping). Stats partial over cg's 32
// classes -> 2 slots per (cs,row), merged in finalize. DMA staging +
// baked-L2E30 stats carried over from R7.
// ---------------------------------------------------------------------------
__global__ __launch_bounds__(256, 4)
void gemm_stats9_kernel(const unsigned short* __restrict__ asw,
                        const unsigned short* __restrict__ wsw,
                        float2* __restrict__ pslot)
{
    __shared__ __align__(16) char lds[49152];       // 2 x 24KB chunk dbuf
    const int bid  = blockIdx.x;
    const int cs   = bid & 127;          // class split (bid%8 == cs%8 -> XCD)
    const int rb   = bid >> 7;           // row block 0..15 (64 rows each)
    const int tid  = threadIdx.x;
    const int wv   = tid >> 6;
    const int rg   = wv >> 1;            // row group (32 rows)
    const int cg   = wv & 1;             // class group (32 classes of chunk)
    const int lane = tid & 63;
    const int quad = lane >> 4, mrow = lane & 15;

    // persistent A fragments: 32 x-rows * 192 k = 48 VGPRs
    bf16x8 xfr[2][6];
    {
        const unsigned short* ab = asw + (size_t)rb * 12288;
        #pragma unroll
        for (int a = 0; a < 2; ++a)
            #pragma unroll
            for (int ks = 0; ks < 6; ++ks)
                xfr[a][ks] = *(const bf16x8*)(ab +
                    (size_t)((ks * 4 + quad) * 64 + rg * 32 + a * 16 + mrow) * 8);
    }

    const int nch = 12 + (cs < 32 ? 1 : 0);
    const char* wp0 = (const char*)(wsw
                    + (size_t)(cs * 12 + (cs < 32 ? cs : 32)) * 12288);

    float s_acc[2][4];
    float m_acc[2][4];
    #pragma unroll
    for (int a = 0; a < 2; ++a)
        #pragma unroll
        for (int r = 0; r < 4; ++r) { s_acc[a][r] = 0.f; m_acc[a][r] = -1e30f; }

    // prologue: DMA chunk 0 into buf0 (per-lane src, wave-uniform dest)
    {
        const char* g = wp0 + wv * 6144 + lane * 16;
        char* l = lds + wv * 6144;
        #pragma unroll
        for (int i = 0; i < 6; ++i)
            gload_lds16(g + i * 1024, l + i * 1024);
    }
    __syncthreads();

    #pragma unroll 1
    for (int c = 0; c < nch; ++c) {
        // DMA chunk c+1 into the other buffer (full-chunk compute cover)
        if (c + 1 < nch) {
            const char* g = wp0 + (size_t)(c + 1) * 24576 + wv * 6144 + lane * 16;
            char* l = lds + ((c + 1) & 1) * 24576 + wv * 6144;
            #pragma unroll
            for (int i = 0; i < 6; ++i)
                gload_lds16(g + i * 1024, l + i * 1024);
        }

        const char* bb = lds + (c & 1) * 24576;
        floatx4 acc[2][2];
        #pragma unroll
        for (int a = 0; a < 2; ++a)
            #pragma unroll
            for (int ni = 0; ni < 2; ++ni) {
                floatx4 z = {0.f, 0.f, 0.f, 0.f};
                acc[a][ni] = z;
            }
        #pragma unroll
        for (int ks = 0; ks < 6; ++ks) {
            const char* sb = bb
                + (size_t)((ks * 4 + quad) * 64 + cg * 32 + mrow) * 16;
            bf16x8 b0 = *(const bf16x8*)(sb);
            bf16x8 b1 = *(const bf16x8*)(sb + 256);   // ni=1: +16 classes
            __builtin_amdgcn_s_setprio(1);
            acc[0][0] = __builtin_amdgcn_mfma_f32_16x16x32_bf16(
                xfr[0][ks], b0, acc[0][0], 0, 0, 0);
            acc[0][1] = __builtin_amdgcn_mfma_f32_16x16x32_bf16(
                xfr[0][ks], b1, acc[0][1], 0, 0, 0);
            acc[1][0] = __builtin_amdgcn_mfma_f32_16x16x32_bf16(
                xfr[1][ks], b0, acc[1][0], 0, 0, 0);
            acc[1][1] = __builtin_amdgcn_mfma_f32_16x16x32_bf16(
                xfr[1][ks], b1, acc[1][1], 0, 0, 0);
            __builtin_amdgcn_s_setprio(0);
        }
        // stats: no fmaf (L2E30 baked into A); exp2 + add + max per score
        #pragma unroll
        for (int a = 0; a < 2; ++a)
            #pragma unroll
            for (int r = 0; r < 4; ++r) {
                float v0 = acc[a][0][r], v1 = acc[a][1][r];
                m_acc[a][r] = fmaxf(fmaxf(v0, v1), m_acc[a][r]);
                s_acc[a][r] += fexp2(v0) + fexp2(v1);
            }
        __syncthreads();   // vmcnt(0) drain = DMA complete; buffer handoff
    }

    // ONE cross-lane reduce per kernel + fp32 write (2 partial slots per cs)
    const int rowb = rb * 64 + rg * 32;
    const int sidx = cs * 2 + cg;
    #pragma unroll
    for (int a = 0; a < 2; ++a)
        #pragma unroll
        for (int r = 0; r < 4; ++r) {
            float s = s_acc[a][r], m = m_acc[a][r];
            s += ror16<1>(s); s += ror16<2>(s); s += ror16<4>(s); s += ror16<8>(s);
            m = fmaxf(m, ror16<1>(m)); m = fmaxf(m, ror16<2>(m));
            m = fmaxf(m, ror16<4>(m)); m = fmaxf(m, ror16<8>(m));
            if (mrow == 0)
                pslot[(size_t)sidx * B_ROWS + rowb + a * 16 + quad * 4 + r] =
                    make_float2(m, s);
        }
}

// ---------------------------------------------------------------------------
// finalize2: merge 256 fp32 slots/row. Stats in L2E30-scaled units:
// true sum = L * exp(-30); max-cos threshold: t_mod > Mc * ln2.
// ---------------------------------------------------------------------------
__global__ __launch_bounds__(256)
void finalize2_kernel(const float2* __restrict__ pslot,
                      const float* __restrict__ x, const float* __restrict__ w,
                      const int* __restrict__ label,
                      float* __restrict__ accum, float* __restrict__ out)
{
    __shared__ float2 red[8][32];
    const int t = threadIdx.x, rr = t & 31, g = t >> 5;
    {
        const int row = blockIdx.x * 32 + rr;
        float M = -1e30f, L = 0.f;
        #pragma unroll
        for (int s = 0; s < NSLOT2 / 8; ++s) {
            float2 p = pslot[(size_t)(s * 8 + g) * B_ROWS + row];
            M = fmaxf(M, p.x);
            L += p.y;
        }
        red[g][rr] = make_float2(M, L);
    }
    __syncthreads();
    if (t < 32) {
        const int row = blockIdx.x * 32 + t;
        float Mc = -1e30f, L = 0.f;
        #pragma unroll
        for (int g2 = 0; g2 < 8; ++g2) {
            float2 p = red[g2][t];
            Mc = fmaxf(Mc, p.x);
            L += p.y;
        }

        const int lab = label[row];
        const float4* xr = (const float4*)(x + (size_t)row * DIM);
        const float4* wr = (const float4*)(w + (size_t)lab * DIM);
        float dot = 0.f, nx = 0.f, nw = 0.f;
        #pragma unroll
        for (int q = 0; q < 48; ++q) {
            float4 a = xr[q], b = wr[q];
            dot += a.x * b.x + a.y * b.y + a.z * b.z + a.w * b.w;
            nx  += a.x * a.x + a.y * a.y + a.z * a.z + a.w * a.w;
            nw  += b.x * b.x + b.y * b.y + b.z * b.z + b.w * b.w;
        }
        float cosl    = dot / fmaxf(sqrtf(nx) * sqrtf(nw), 1e-12f);
        float t_plain = S_SCALE * cosl;
        float sine    = sqrtf(fmaxf(0.f, fminf(1.f, 1.f - cosl * cosl)));
        float phi     = cosl * COS_M - sine * SIN_M;
        float modv    = ((cosl - TH_C) > 0.f) ? phi : (cosl - MM_C);
        float t_mod   = S_SCALE * modv;

        float Ladj = L * EXPM30 - __expf(t_plain - 30.0f) + __expf(t_mod - 30.0f);
        Ladj = fmaxf(Ladj, 1e-37f);
        float loss = (30.0f + logf(Ladj)) - t_mod;
        float corr = (t_mod > Mc * LN2_C) ? 1.f : 0.f;

        #pragma unroll
        for (int off = 16; off > 0; off >>= 1) {
            loss += __shfl_xor(loss, off);
            corr += __shfl_xor(corr, off);
        }
        if (t == 0) {
            atomicAdd(&accum[0], loss);
            atomicAdd(&accum[1], corr);
            __threadfence();
            int old = atomicAdd((int*)accum + 2, 1);
            if (old == (int)gridDim.x - 1) {
                float a0 = atomicAdd(&accum[0], 0.0f);
                float a1 = atomicAdd(&accum[1], 0.0f);
                out[0] = a0 * (1.0f / (float)B_ROWS);
                out[1] = a1 * (100.0f / (float)B_ROWS);
            }
        }
    }
}

// ===========================================================================
// OLD PATH (verified fallback, used only if workspace is too small)
// ===========================================================================

__global__ __launch_bounds__(256)
void prep_kernel(const float* __restrict__ x, unsigned short* __restrict__ asw,
                 float* __restrict__ accum)
{
    const int ab = blockIdx.x;
    const int t = threadIdx.x;
    if (ab == 0 && t < 4) accum[t] = 0.0f;
    const int r = t >> 1, half = t & 1;
    const int row = ab * 128 + r;
    const int c = ab * 2 + (r >> 6);
    const int r64 = r & 63;

    float4 buf[24];
    float s = 0.f;
    const float4* sp = (const float4*)(x + (size_t)row * DIM) + half * 24;
    #pragma unroll
    for (int q = 0; q < 24; ++q) {
        float4 v = sp[q];
        buf[q] = v;
        s += v.x * v.x + v.y * v.y + v.z * v.z + v.w * v.w;
    }
    s += __shfl_xor(s, 1);
    const float inv = 1.0f / fmaxf(sqrtf(s), 1e-12f);
    #pragma unroll
    for (int j = 0; j < 12; ++j) {
        const int k8 = half * 12 + j;
        uint4 o;
        float4 a0 = buf[2 * j], a1 = buf[2 * j + 1];
        o.x = pack2(a0.x * inv, a0.y * inv);
        o.y = pack2(a0.z * inv, a0.w * inv);
        o.z = pack2(a1.x * inv, a1.y * inv);
        o.w = pack2(a1.z * inv, a1.w * inv);
        *(uint4*)(asw + ((size_t)c * ASEG_CH + k8 * 64 + r64) * 8) = o;
    }
}

__global__ __launch_bounds__(256, 3)
void gemm_stats_kernel(const float* __restrict__ w,
                       const unsigned short* __restrict__ asw,
                       unsigned int* __restrict__ pslot)
{
    __shared__ __align__(16) char lds[49152];
    const int tid  = threadIdx.x;
    const int wave = tid >> 6;
    const int lane = tid & 63;
    const int quad = lane >> 4;
    const int mrow = lane & 15;
    const int rg   = wave >> 1;
    const int cgr  = wave & 1;

    {
        const int r = tid >> 1, half = tid & 1;
        const int col = blockIdx.x * 128 + r;
        const bool live = (col < NCLS);
        float4 buf[24];
        float s = 0.f;
        if (live) {
            const float4* sp = (const float4*)(w + (size_t)col * DIM) + half * 24;
            #pragma unroll
            for (int q = 0; q < 24; ++q) {
                float4 v = sp[q];
                buf[q] = v;
                s += v.x * v.x + v.y * v.y + v.z * v.z + v.w * v.w;
            }
        }
        s += __shfl_xor(s, 1);
        const float inv = live ? (1.0f / fmaxf(sqrtf(s), 1e-12f)) : 0.0f;
        #pragma unroll
        for (int j = 0; j < 12; ++j) {
            const int k8 = half * 12 + j;
            uint4 o = make_uint4(0u, 0u, 0u, 0u);
            if (live) {
                float4 a0 = buf[2 * j], a1 = buf[2 * j + 1];
                o.x = pack2(a0.x * inv, a0.y * inv);
                o.y = pack2(a0.z * inv, a0.w * inv);
                o.z = pack2(a1.x * inv, a1.y * inv);
                o.w = pack2(a1.z * inv, a1.w * inv);
            }
            *(uint4*)(lds + (size_t)(k8 * 128 + r) * 16) = o;
        }
    }
    __syncthreads();

    bf16x8 bfr[6][4];
    #pragma unroll
    for (int ks = 0; ks < 6; ++ks)
        #pragma unroll
        for (int ni = 0; ni < 4; ++ni)
            bfr[ks][ni] = *(const bf16x8*)(lds +
                (((ks * 4 + quad) * 128) + cgr * 64 + ni * 16 + mrow) * 16);

    const int slot = blockIdx.x * 2 + cgr;
    #pragma unroll 2
    for (int c = 0; c < NCHUNKR; ++c) {
        const unsigned short* ab = asw + (size_t)c * ASEG_CH * 8;
        floatx4 acc[2][4];
        #pragma unroll
        for (int mi = 0; mi < 2; ++mi)
            #pragma unroll
            for (int ni = 0; ni < 4; ++ni) {
                floatx4 z = {0.f, 0.f, 0.f, 0.f};
                acc[mi][ni] = z;
            }
        #pragma unroll
        for (int ks = 0; ks < 6; ++ks) {
            bf16x8 a0 = *(const bf16x8*)(ab +
                (size_t)(((ks * 4 + quad) * 64) + rg * 32 + mrow) * 8);
            bf16x8 a1 = *(const bf16x8*)(ab +
                (size_t)(((ks * 4 + quad) * 64) + rg * 32 + 16 + mrow) * 8);
            #pragma unroll
            for (int ni = 0; ni < 4; ++ni)
                acc[0][ni] = __builtin_amdgcn_mfma_f32_16x16x32_bf16(
                    a0, bfr[ks][ni], acc[0][ni], 0, 0, 0);
            #pragma unroll
            for (int ni = 0; ni < 4; ++ni)
                acc[1][ni] = __builtin_amdgcn_mfma_f32_16x16x32_bf16(
                    a1, bfr[ks][ni], acc[1][ni], 0, 0, 0);
        }

        #pragma unroll
        for (int mi = 0; mi < 2; ++mi)
            #pragma unroll
            for (int r = 0; r < 4; ++r) {
                float v0 = acc[mi][0][r], v1 = acc[mi][1][r];
                float v2 = acc[mi][2][r], v3 = acc[mi][3][r];
                float m = fmaxf(fmaxf(v0, v1), fmaxf(v2, v3));
                float s = fexp2(fmaf(v0, L2E30, -L2E30))
                        + fexp2(fmaf(v1, L2E30, -L2E30))
                        + fexp2(fmaf(v2, L2E30, -L2E30))
                        + fexp2(fmaf(v3, L2E30, -L2E30));
                s += ror16<1>(s); s += ror16<2>(s);
                s += ror16<4>(s); s += ror16<8>(s);
                m = fmaxf(m, ror16<1>(m)); m = fmaxf(m, ror16<2>(m));
                m = fmaxf(m, ror16<4>(m)); m = fmaxf(m, ror16<8>(m));
                if (mrow == mi * 4 + r)
                    pslot[(size_t)slot * B_ROWS +
                          c * 64 + rg * 32 + mi * 16 + quad * 4 + r] = pack2(m, s);
            }
    }
}

__global__ __launch_bounds__(256)
void finalize_kernel(const unsigned int* __restrict__ pslot,
                     const float* __restrict__ x, const float* __restrict__ w,
                     const int* __restrict__ label,
                     float* __restrict__ accum, float* __restrict__ out)
{
    __shared__ float2 red[8][32];
    const int t = threadIdx.x, rr = t & 31, g = t >> 5;
    {
        const int row = blockIdx.x * 32 + rr;
        float M = -1e30f, L = 0.f;
        for (int s = g; s < NSLOT; s += 8) {
            unsigned int u = pslot[(size_t)s * B_ROWS + row];
            M = fmaxf(M, __uint_as_float(u << 16));
            L += __uint_as_float(u & 0xFFFF0000u);
        }
        red[g][rr] = make_float2(M, L);
    }
    __syncthreads();
    if (t < 32) {
        const int row = blockIdx.x * 32 + t;
        float Mc = -1e30f, L = 0.f;
        #pragma unroll
        for (int g2 = 0; g2 < 8; ++g2) {
            float2 p = red[g2][t];
            Mc = fmaxf(Mc, p.x);
            L += p.y;
        }

        const int lab = label[row];
        const float4* xr = (const float4*)(x + (size_t)row * DIM);
        const float4* wr = (const float4*)(w + (size_t)lab * DIM);
        float dot = 0.f, nx = 0.f, nw = 0.f;
        #pragma unroll
        for (int q = 0; q < 48; ++q) {
            float4 a = xr[q], b = wr[q];
            dot += a.x * b.x + a.y * b.y + a.z * b.z + a.w * b.w;
            nx  += a.x * a.x + a.y * a.y + a.z * a.z + a.w * a.w;
            nw  += b.x * b.x + b.y * b.y + b.z * b.z + b.w * b.w;
        }
        float cosl    = dot / fmaxf(sqrtf(nx) * sqrtf(nw), 1e-12f);
        float t_plain = S_SCALE * cosl;
        float sine    = sqrtf(fmaxf(0.f, fminf(1.f, 1.f - cosl * cosl)));
        float phi     = cosl * COS_M - sine * SIN_M;
        float modv    = ((cosl - TH_C) > 0.f) ? phi : (cosl - MM_C);
        float t_mod   = S_SCALE * modv;

        float Ladj = L - __expf(t_plain - 30.0f) + __expf(t_mod - 30.0f);
        Ladj = fmaxf(Ladj, 1e-37f);
        float loss = (30.0f + logf(Ladj)) - t_mod;
        float corr = (t_mod > S_SCALE * Mc) ? 1.f : 0.f;

        #pragma unroll
        for (int off = 16; off > 0; off >>= 1) {
            loss += __shfl_xor(loss, off);
            corr += __shfl_xor(corr, off);
        }
        if (t == 0) {
            atomicAdd(&accum[0], loss);
            atomicAdd(&accum[1], corr);
            __threadfence();
            int old = atomicAdd((int*)accum + 2, 1);
            if (old == (int)gridDim.x - 1) {
                float a0 = atomicAdd(&accum[0], 0.0f);
                float a1 = atomicAdd(&accum[1], 0.0f);
                out[0] = a0 * (1.0f / (float)B_ROWS);
                out[1] = a1 * (100.0f / (float)B_ROWS);
            }
        }
    }
}

// ---------------------------------------------------------------------------
extern "C" void kernel_launch(void* const* d_in, const int* in_sizes, int n_in,
                              void* d_out, int out_size, void* d_ws, size_t ws_size,
                              hipStream_t stream)
{
    const float* x     = (const float*)d_in[0];
    const float* w     = (const float*)d_in[1];
    const int*   label = (const int*)d_in[2];
    float* out = (float*)d_out;

    char* ws = (char*)d_ws;
    float* accum = (float*)ws;
    unsigned short* asw = (unsigned short*)(ws + 256);
    const size_t asw_bytes = (size_t)NCHUNKR * ASEG_CH * 16;           // 393216

    const size_t wsw_bytes    = (size_t)NCHUNKC * 24 * 64 * 16;       // 38535168
    const size_t pslot2_bytes = (size_t)NSLOT2 * B_ROWS * 8;          // 2097152
    const size_t need_new = 256 + asw_bytes + wsw_bytes + pslot2_bytes;

    if (ws_size >= need_new) {
        unsigned short* wsw = (unsigned short*)(ws + 256 + asw_bytes);
        float2* pslot2 = (float2*)(ws + 256 + asw_bytes + wsw_bytes);
        pack2_kernel<<<dim3(PACK_GRID), dim3(256), 0, stream>>>(x, w, asw, wsw, accum);
        gemm_stats9_kernel<<<dim3(16 * CSPLIT), dim3(256), 0, stream>>>(asw, wsw, pslot2);
        finalize2_kernel<<<dim3(B_ROWS / 32), dim3(256), 0, stream>>>(
            pslot2, x, w, label, accum, out);
    } else {
        unsigned int* pslot = (unsigned int*)(ws + 256 + asw_bytes);
        prep_kernel<<<dim3(8), dim3(256), 0, stream>>>(x, asw, accum);
        gemm_stats_kernel<<<dim3(NTILE_B), dim3(256), 0, stream>>>(w, asw, pslot);
        finalize_kernel<<<dim3(B_ROWS / 32), dim3(256), 0, stream>>>(
            pslot, x, w, label, accum, out);
    }
}

// Round 9
// 158.547 us; speedup vs baseline: 1.0673x; 1.0673x over previous
//
#include <hip/hip_runtime.h>
#include <math.h>

#define B_ROWS   1024
#define DIM      192
#define NCLS     100000
#define S_SCALE  30.0f
#define COS_M    0.98006657784124163f
#define SIN_M    0.19866933079506122f
#define TH_C     (-0.98006657784124163f)
#define MM_C     0.039733866159012243f
#define L2E30    43.2808512266689f      // 30 * log2(e)
#define EXPM30   9.357622968840175e-14f // exp(-30) = 2^-L2E30
#define LN2_C    0.69314718055994531f

// ---- old-path constants (kept as fallback when workspace is small) ----
#define NTILE_B  784
#define NCHUNKR  16
#define ASEG_CH  1536
#define NSLOT    1568

// ---- new-path constants ----
#define NCHUNKC  1568     // 64-class chunks total (1568*64 = 100352)
#define CSPLIT   128
#define NSLOT2   128
#define PACK_WGRID 3136
#define PACK_GRID  3168

typedef float floatx4 __attribute__((ext_vector_type(4)));
typedef __bf16 bf16x8 __attribute__((ext_vector_type(8)));

#define AS1 __attribute__((address_space(1)))
#define AS3 __attribute__((address_space(3)))

__device__ __forceinline__ unsigned int f2bf(float x) {
    unsigned int u = __float_as_uint(x);
    u = (u + 0x7fffu + ((u >> 16) & 1u)) >> 16;   // RNE
    return u;
}
__device__ __forceinline__ unsigned int pack2(float lo, float hi) {
    return f2bf(lo) | (f2bf(hi) << 16);
}
__device__ __forceinline__ float fexp2(float x) {
#if __has_builtin(__builtin_amdgcn_exp2f)
    return __builtin_amdgcn_exp2f(x);
#else
    float r; __asm__("v_exp_f32 %0, %1" : "=v"(r) : "v"(x)); return r;
#endif
}
template <int N>
__device__ __forceinline__ float ror16(float x) {
    return __int_as_float(__builtin_amdgcn_mov_dpp(
        __float_as_int(x), 0x120 | N, 0xF, 0xF, false));
}
// async global->LDS DMA, 16B/lane: wave-uniform LDS base + per-lane global
// src; direct addrspacecasts (R7-verified safe & fast).
__device__ __forceinline__ void gload_lds16(const void* g, void* l) {
    __builtin_amdgcn_global_load_lds(
        (const AS1 unsigned int*)g, (AS3 unsigned int*)l, 16, 0, 0);
}
// counted vmcnt wait (T4): never drain to 0 mid-loop. pend = future chunks
// in flight (6 DMA loads each). sched_barrier(0) pins compiler motion
// across the inline asm (guide rule 18).
__device__ __forceinline__ void waitcnt_vm(int pend) {
    if (pend >= 2)      asm volatile("s_waitcnt vmcnt(12)" ::: "memory");
    else if (pend == 1) asm volatile("s_waitcnt vmcnt(6)"  ::: "memory");
    else                asm volatile("s_waitcnt vmcnt(0)"  ::: "memory");
    __builtin_amdgcn_sched_barrier(0);
}

// ===========================================================================
// NEW PATH
// ===========================================================================

// ---------------------------------------------------------------------------
// pack2 (R6/R7-verified): normalize + bf16 pack + MFMA-order swizzle,
// coalesced 512B stores via LDS transpose, XCD-aligned block permutation
// (chunk cc written on XCD cs(cc)%8 = reader's XCD). x-side bakes L2E30.
// ---------------------------------------------------------------------------
__global__ __launch_bounds__(256)
void pack2_kernel(const float* __restrict__ x, const float* __restrict__ w,
                  unsigned short* __restrict__ asw, unsigned short* __restrict__ wsw,
                  float* __restrict__ accum)
{
    __shared__ uint4 lds_pk[32][25];     // +1 pad: break phase-2 bank aliasing
    const int bid = blockIdx.x;
    const int t = threadIdx.x;
    const int r = t >> 3, oct = t & 7;

    const float* src;
    unsigned short* dstc;                // chunk base in destination
    int rowbase, half;
    bool wside;
    if (bid < PACK_WGRID) {
        // XCD class k = bid&7 owns all (cc,half) with cs(cc)%8 == k.
        const int k = bid & 7, j = bid >> 3;   // j in [0,392)
        int cs, cc, h;
        if (j < 104) {                   // cs < 32: 13 chunks x 2 halves = 26
            const int i = j / 26; h = j % 26;
            cs = k + 8 * i;  cc = cs * 13 + (h >> 1);
        } else {                         // cs >= 32: 12 chunks x 2 halves = 24
            const int j2 = j - 104;
            const int i = 4 + j2 / 24; h = j2 % 24;
            cs = k + 8 * i;  cc = 416 + (cs - 32) * 12 + (h >> 1);
        }
        half = h & 1;
        rowbase = cc * 64 + half * 32;
        src = w;  dstc = wsw + (size_t)cc * 12288;  wside = true;
    } else {
        const int xb = bid - PACK_WGRID;            // 0..31
        half = xb & 1;
        rowbase = xb * 32;
        src = x;  dstc = asw + (size_t)(xb >> 1) * 12288;  wside = false;
        if (bid == PACK_WGRID && t < 4) accum[t] = 0.0f;
    }

    const int row = rowbase + r;
    const bool live = !wside || (row < NCLS);
    float4 buf[6];
    float s = 0.f;
    if (live) {
        const float4* sp = (const float4*)(src + (size_t)row * DIM) + oct * 6;
        #pragma unroll
        for (int q = 0; q < 6; ++q) {
            float4 v = sp[q];
            buf[q] = v;
            s += v.x * v.x + v.y * v.y + v.z * v.z + v.w * v.w;
        }
    } else {
        #pragma unroll
        for (int q = 0; q < 6; ++q) buf[q] = make_float4(0.f, 0.f, 0.f, 0.f);
    }
    s += __shfl_xor(s, 1);
    s += __shfl_xor(s, 2);
    s += __shfl_xor(s, 4);
    float inv = live ? (1.0f / fmaxf(sqrtf(s), 1e-12f)) : 0.0f;
    if (!wside) inv *= L2E30;            // bake 30*log2(e) into x-side

    #pragma unroll
    for (int j = 0; j < 3; ++j) {
        const int k8 = oct * 3 + j;
        uint4 o;
        float4 a0 = buf[2 * j], a1 = buf[2 * j + 1];
        o.x = pack2(a0.x * inv, a0.y * inv);
        o.y = pack2(a0.z * inv, a0.w * inv);
        o.z = pack2(a1.x * inv, a1.y * inv);
        o.w = pack2(a1.z * inv, a1.w * inv);
        lds_pk[r][k8] = o;
    }
    __syncthreads();
    // coalesced store: 32 consecutive lanes write 32 consecutive 16B blocks
    #pragma unroll
    for (int j = 0; j < 3; ++j) {
        const int flat = j * 256 + t;                // [0,768)
        const int sseg = flat >> 5, rr = flat & 31;  // seg 0..23, row 0..31
        *(uint4*)(dstc + ((size_t)(sseg * 64) + half * 32 + rr) * 8)
            = lds_pk[rr][sseg];
    }
}

// ---------------------------------------------------------------------------
// gemm_stats10: stats8 geometry (512 blocks, M=64/wave, 16x16 MFMA, LDS-
// broadcast B via DMA) + COUNTED-VMCNT 3-BUFFER PIPELINE. R8 post-mortem:
// stats8's __syncthreads drains vmcnt(0) each chunk — the just-issued DMA
// round-trip lands on the critical path, and the 2 phase-locked blocks/CU
// stall together. Now: iter c issues DMA(c+2)->buf[(c+2)%3], waits
// vmcnt(12) (chunk c landed, 12 newer loads REMAIN IN FLIGHT), raw
// s_barrier, computes buf[c%3] under setprio(1), raw s_barrier (read-done
// guard before buf reuse at c+1's issue). vmcnt never drains mid-loop
// (T3/T4, m218); setprio pays once the schedule phase-splits (T5, m218b).
// LDS 72KB -> still 2 blocks/CU.
// ---------------------------------------------------------------------------
__global__ __launch_bounds__(256, 2)
void gemm_stats10_kernel(const unsigned short* __restrict__ asw,
                         const unsigned short* __restrict__ wsw,
                         float2* __restrict__ pslot)
{
    __shared__ __align__(16) char lds[73728];       // 3 x 24KB chunk bufs
    const int bid  = blockIdx.x;
    const int cs   = bid & 127;          // class split (bid%8 == cs%8 -> XCD)
    const int rb   = bid >> 7;           // row block 0..3 (256 rows each)
    const int tid  = threadIdx.x;
    const int wv   = tid >> 6;
    const int lane = tid & 63;
    const int quad = lane >> 4, mrow = lane & 15;

    // persistent A fragments: 64 x-rows * 192 k = 96 VGPRs
    bf16x8 xfr[4][6];
    {
        const unsigned short* ab = asw + (size_t)(rb * 4 + wv) * 12288;
        #pragma unroll
        for (int a = 0; a < 4; ++a)
            #pragma unroll
            for (int ks = 0; ks < 6; ++ks)
                xfr[a][ks] = *(const bf16x8*)(ab +
                    (size_t)((ks * 4 + quad) * 64 + a * 16 + mrow) * 8);
    }

    const int nch = 12 + (cs < 32 ? 1 : 0);
    const char* wp0 = (const char*)(wsw
                    + (size_t)(cs * 12 + (cs < 32 ? cs : 32)) * 12288);
    const int soff = wv * 6144 + lane * 16;   // global per-lane offset
    const int loff = wv * 6144;               // wave-uniform LDS offset

    float s_acc[4][4];
    float m_acc[4][4];
    #pragma unroll
    for (int a = 0; a < 4; ++a)
        #pragma unroll
        for (int r = 0; r < 4; ++r) { s_acc[a][r] = 0.f; m_acc[a][r] = -1e30f; }

    // prologue: DMA chunk 0 -> buf0, chunk 1 -> buf1 (12 loads in flight)
    {
        const char* g0 = wp0 + soff;
        #pragma unroll
        for (int i = 0; i < 6; ++i)
            gload_lds16(g0 + i * 1024, lds + loff + i * 1024);
        const char* g1 = wp0 + 24576 + soff;
        #pragma unroll
        for (int i = 0; i < 6; ++i)
            gload_lds16(g1 + i * 1024, lds + 24576 + loff + i * 1024);
    }

    #pragma unroll 1
    for (int c = 0; c < nch; ++c) {
        // issue DMA for chunk c+2 into buf[(c+2)%3] (chunk c's old buffer
        // slot was released by the previous iteration's trailing barrier)
        if (c + 2 < nch) {
            const char* g = wp0 + (size_t)(c + 2) * 24576 + soff;
            char* l = lds + ((c + 2) % 3) * 24576 + loff;
            #pragma unroll
            for (int i = 0; i < 6; ++i)
                gload_lds16(g + i * 1024, l + i * 1024);
        }
        // counted wait: chunk c's 6 loads (oldest) done; newer stay in flight
        int pend = nch - 1 - c; if (pend > 2) pend = 2;
        waitcnt_vm(pend);
        __builtin_amdgcn_s_barrier();    // all waves' slices of chunk c ready

        const char* bb = lds + (c % 3) * 24576;
        floatx4 acc[4][4];
        #pragma unroll
        for (int a = 0; a < 4; ++a)
            #pragma unroll
            for (int ni = 0; ni < 4; ++ni) {
                floatx4 z = {0.f, 0.f, 0.f, 0.f};
                acc[a][ni] = z;
            }
        #pragma unroll
        for (int ks = 0; ks < 6; ++ks) {
            const char* sb = bb + (size_t)((ks * 4 + quad) * 64 + mrow) * 16;
            bf16x8 b0 = *(const bf16x8*)(sb);
            bf16x8 b1 = *(const bf16x8*)(sb + 256);
            bf16x8 b2 = *(const bf16x8*)(sb + 512);
            bf16x8 b3 = *(const bf16x8*)(sb + 768);
            __builtin_amdgcn_s_setprio(1);
            #pragma unroll
            for (int a = 0; a < 4; ++a) {
                acc[a][0] = __builtin_amdgcn_mfma_f32_16x16x32_bf16(
                    xfr[a][ks], b0, acc[a][0], 0, 0, 0);
                acc[a][1] = __builtin_amdgcn_mfma_f32_16x16x32_bf16(
                    xfr[a][ks], b1, acc[a][1], 0, 0, 0);
                acc[a][2] = __builtin_amdgcn_mfma_f32_16x16x32_bf16(
                    xfr[a][ks], b2, acc[a][2], 0, 0, 0);
                acc[a][3] = __builtin_amdgcn_mfma_f32_16x16x32_bf16(
                    xfr[a][ks], b3, acc[a][3], 0, 0, 0);
            }
            __builtin_amdgcn_s_setprio(0);
        }
        // stats: no fmaf (L2E30 baked into A); exp2 + add + max per score
        #pragma unroll
        for (int a = 0; a < 4; ++a)
            #pragma unroll
            for (int r = 0; r < 4; ++r) {
                float v0 = acc[a][0][r], v1 = acc[a][1][r];
                float v2 = acc[a][2][r], v3 = acc[a][3][r];
                m_acc[a][r] = fmaxf(fmaxf(fmaxf(fmaxf(v0, v1), v2), v3),
                                    m_acc[a][r]);
                s_acc[a][r] += (fexp2(v0) + fexp2(v1))
                             + (fexp2(v2) + fexp2(v3));
            }
        __builtin_amdgcn_s_barrier();    // read-done: buf[c%3] may be reused
    }

    // ONE cross-lane reduce per kernel + fp32 write
    const int rowb = rb * 256 + wv * 64;
    #pragma unroll
    for (int a = 0; a < 4; ++a)
        #pragma unroll
        for (int r = 0; r < 4; ++r) {
            float s = s_acc[a][r], m = m_acc[a][r];
            s += ror16<1>(s); s += ror16<2>(s); s += ror16<4>(s); s += ror16<8>(s);
            m = fmaxf(m, ror16<1>(m)); m = fmaxf(m, ror16<2>(m));
            m = fmaxf(m, ror16<4>(m)); m = fmaxf(m, ror16<8>(m));
            if (mrow == 0)
                pslot[(size_t)cs * B_ROWS + rowb + a * 16 + quad * 4 + r] =
                    make_float2(m, s);
        }
}

// ---------------------------------------------------------------------------
// finalize2: merge 128 fp32 slots/row. Stats in L2E30-scaled units:
// true sum = L * exp(-30); max-cos threshold: t_mod > Mc * ln2. (Verified.)
// ---------------------------------------------------------------------------
__global__ __launch_bounds__(256)
void finalize2_kernel(const float2* __restrict__ pslot,
                      const float* __restrict__ x, const float* __restrict__ w,
                      const int* __restrict__ label,
                      float* __restrict__ accum, float* __restrict__ out)
{
    __shared__ float2 red[8][32];
    const int t = threadIdx.x, rr = t & 31, g = t >> 5;
    {
        const int row = blockIdx.x * 32 + rr;
        float M = -1e30f, L = 0.f;
        #pragma unroll
        for (int s = 0; s < NSLOT2 / 8; ++s) {
            float2 p = pslot[(size_t)(s * 8 + g) * B_ROWS + row];
            M = fmaxf(M, p.x);
            L += p.y;
        }
        red[g][rr] = make_float2(M, L);
    }
    __syncthreads();
    if (t < 32) {
        const int row = blockIdx.x * 32 + t;
        float Mc = -1e30f, L = 0.f;
        #pragma unroll
        for (int g2 = 0; g2 < 8; ++g2) {
            float2 p = red[g2][t];
            Mc = fmaxf(Mc, p.x);
            L += p.y;
        }

        const int lab = label[row];
        const float4* xr = (const float4*)(x + (size_t)row * DIM);
        const float4* wr = (const float4*)(w + (size_t)lab * DIM);
        float dot = 0.f, nx = 0.f, nw = 0.f;
        #pragma unroll
        for (int q = 0; q < 48; ++q) {
            float4 a = xr[q], b = wr[q];
            dot += a.x * b.x + a.y * b.y + a.z * b.z + a.w * b.w;
            nx  += a.x * a.x + a.y * a.y + a.z * a.z + a.w * a.w;
            nw  += b.x * b.x + b.y * b.y + b.z * b.z + b.w * b.w;
        }
        float cosl    = dot / fmaxf(sqrtf(nx) * sqrtf(nw), 1e-12f);
        float t_plain = S_SCALE * cosl;
        float sine    = sqrtf(fmaxf(0.f, fminf(1.f, 1.f - cosl * cosl)));
        float phi     = cosl * COS_M - sine * SIN_M;
        float modv    = ((cosl - TH_C) > 0.f) ? phi : (cosl - MM_C);
        float t_mod   = S_SCALE * modv;

        float Ladj = L * EXPM30 - __expf(t_plain - 30.0f) + __expf(t_mod - 30.0f);
        Ladj = fmaxf(Ladj, 1e-37f);
        float loss = (30.0f + logf(Ladj)) - t_mod;
        float corr = (t_mod > Mc * LN2_C) ? 1.f : 0.f;

        #pragma unroll
        for (int off = 16; off > 0; off >>= 1) {
            loss += __shfl_xor(loss, off);
            corr += __shfl_xor(corr, off);
        }
        if (t == 0) {
            atomicAdd(&accum[0], loss);
            atomicAdd(&accum[1], corr);
            __threadfence();
            int old = atomicAdd((int*)accum + 2, 1);
            if (old == (int)gridDim.x - 1) {
                float a0 = atomicAdd(&accum[0], 0.0f);
                float a1 = atomicAdd(&accum[1], 0.0f);
                out[0] = a0 * (1.0f / (float)B_ROWS);
                out[1] = a1 * (100.0f / (float)B_ROWS);
            }
        }
    }
}

// ===========================================================================
// OLD PATH (verified fallback, used only if workspace is too small)
// ===========================================================================

__global__ __launch_bounds__(256)
void prep_kernel(const float* __restrict__ x, unsigned short* __restrict__ asw,
                 float* __restrict__ accum)
{
    const int ab = blockIdx.x;
    const int t = threadIdx.x;
    if (ab == 0 && t < 4) accum[t] = 0.0f;
    const int r = t >> 1, half = t & 1;
    const int row = ab * 128 + r;
    const int c = ab * 2 + (r >> 6);
    const int r64 = r & 63;

    float4 buf[24];
    float s = 0.f;
    const float4* sp = (const float4*)(x + (size_t)row * DIM) + half * 24;
    #pragma unroll
    for (int q = 0; q < 24; ++q) {
        float4 v = sp[q];
        buf[q] = v;
        s += v.x * v.x + v.y * v.y + v.z * v.z + v.w * v.w;
    }
    s += __shfl_xor(s, 1);
    const float inv = 1.0f / fmaxf(sqrtf(s), 1e-12f);
    #pragma unroll
    for (int j = 0; j < 12; ++j) {
        const int k8 = half * 12 + j;
        uint4 o;
        float4 a0 = buf[2 * j], a1 = buf[2 * j + 1];
        o.x = pack2(a0.x * inv, a0.y * inv);
        o.y = pack2(a0.z * inv, a0.w * inv);
        o.z = pack2(a1.x * inv, a1.y * inv);
        o.w = pack2(a1.z * inv, a1.w * inv);
        *(uint4*)(asw + ((size_t)c * ASEG_CH + k8 * 64 + r64) * 8) = o;
    }
}

__global__ __launch_bounds__(256, 3)
void gemm_stats_kernel(const float* __restrict__ w,
                       const unsigned short* __restrict__ asw,
                       unsigned int* __restrict__ pslot)
{
    __shared__ __align__(16) char lds[49152];
    const int tid  = threadIdx.x;
    const int wave = tid >> 6;
    const int lane = tid & 63;
    const int quad = lane >> 4;
    const int mrow = lane & 15;
    const int rg   = wave >> 1;
    const int cgr  = wave & 1;

    {
        const int r = tid >> 1, half = tid & 1;
        const int col = blockIdx.x * 128 + r;
        const bool live = (col < NCLS);
        float4 buf[24];
        float s = 0.f;
        if (live) {
            const float4* sp = (const float4*)(w + (size_t)col * DIM) + half * 24;
            #pragma unroll
            for (int q = 0; q < 24; ++q) {
                float4 v = sp[q];
                buf[q] = v;
                s += v.x * v.x + v.y * v.y + v.z * v.z + v.w * v.w;
            }
        }
        s += __shfl_xor(s, 1);
        const float inv = live ? (1.0f / fmaxf(sqrtf(s), 1e-12f)) : 0.0f;
        #pragma unroll
        for (int j = 0; j < 12; ++j) {
            const int k8 = half * 12 + j;
            uint4 o = make_uint4(0u, 0u, 0u, 0u);
            if (live) {
                float4 a0 = buf[2 * j], a1 = buf[2 * j + 1];
                o.x = pack2(a0.x * inv, a0.y * inv);
                o.y = pack2(a0.z * inv, a0.w * inv);
                o.z = pack2(a1.x * inv, a1.y * inv);
                o.w = pack2(a1.z * inv, a1.w * inv);
            }
            *(uint4*)(lds + (size_t)(k8 * 128 + r) * 16) = o;
        }
    }
    __syncthreads();

    bf16x8 bfr[6][4];
    #pragma unroll
    for (int ks = 0; ks < 6; ++ks)
        #pragma unroll
        for (int ni = 0; ni < 4; ++ni)
            bfr[ks][ni] = *(const bf16x8*)(lds +
                (((ks * 4 + quad) * 128) + cgr * 64 + ni * 16 + mrow) * 16);

    const int slot = blockIdx.x * 2 + cgr;
    #pragma unroll 2
    for (int c = 0; c < NCHUNKR; ++c) {
        const unsigned short* ab = asw + (size_t)c * ASEG_CH * 8;
        floatx4 acc[2][4];
        #pragma unroll
        for (int mi = 0; mi < 2; ++mi)
            #pragma unroll
            for (int ni = 0; ni < 4; ++ni) {
                floatx4 z = {0.f, 0.f, 0.f, 0.f};
                acc[mi][ni] = z;
            }
        #pragma unroll
        for (int ks = 0; ks < 6; ++ks) {
            bf16x8 a0 = *(const bf16x8*)(ab +
                (size_t)(((ks * 4 + quad) * 64) + rg * 32 + mrow) * 8);
            bf16x8 a1 = *(const bf16x8*)(ab +
                (size_t)(((ks * 4 + quad) * 64) + rg * 32 + 16 + mrow) * 8);
            #pragma unroll
            for (int ni = 0; ni < 4; ++ni)
                acc[0][ni] = __builtin_amdgcn_mfma_f32_16x16x32_bf16(
                    a0, bfr[ks][ni], acc[0][ni], 0, 0, 0);
            #pragma unroll
            for (int ni = 0; ni < 4; ++ni)
                acc[1][ni] = __builtin_amdgcn_mfma_f32_16x16x32_bf16(
                    a1, bfr[ks][ni], acc[1][ni], 0, 0, 0);
        }

        #pragma unroll
        for (int mi = 0; mi < 2; ++mi)
            #pragma unroll
            for (int r = 0; r < 4; ++r) {
                float v0 = acc[mi][0][r], v1 = acc[mi][1][r];
                float v2 = acc[mi][2][r], v3 = acc[mi][3][r];
                float m = fmaxf(fmaxf(v0, v1), fmaxf(v2, v3));
                float s = fexp2(fmaf(v0, L2E30, -L2E30))
                        + fexp2(fmaf(v1, L2E30, -L2E30))
                        + fexp2(fmaf(v2, L2E30, -L2E30))
                        + fexp2(fmaf(v3, L2E30, -L2E30));
                s += ror16<1>(s); s += ror16<2>(s);
                s += ror16<4>(s); s += ror16<8>(s);
                m = fmaxf(m, ror16<1>(m)); m = fmaxf(m, ror16<2>(m));
                m = fmaxf(m, ror16<4>(m)); m = fmaxf(m, ror16<8>(m));
                if (mrow == mi * 4 + r)
                    pslot[(size_t)slot * B_ROWS +
                          c * 64 + rg * 32 + mi * 16 + quad * 4 + r] = pack2(m, s);
            }
    }
}

__global__ __launch_bounds__(256)
void finalize_kernel(const unsigned int* __restrict__ pslot,
                     const float* __restrict__ x, const float* __restrict__ w,
                     const int* __restrict__ label,
                     float* __restrict__ accum, float* __restrict__ out)
{
    __shared__ float2 red[8][32];
    const int t = threadIdx.x, rr = t & 31, g = t >> 5;
    {
        const int row = blockIdx.x * 32 + rr;
        float M = -1e30f, L = 0.f;
        for (int s = g; s < NSLOT; s += 8) {
            unsigned int u = pslot[(size_t)s * B_ROWS + row];
            M = fmaxf(M, __uint_as_float(u << 16));
            L += __uint_as_float(u & 0xFFFF0000u);
        }
        red[g][rr] = make_float2(M, L);
    }
    __syncthreads();
    if (t < 32) {
        const int row = blockIdx.x * 32 + t;
        float Mc = -1e30f, L = 0.f;
        #pragma unroll
        for (int g2 = 0; g2 < 8; ++g2) {
            float2 p = red[g2][t];
            Mc = fmaxf(Mc, p.x);
            L += p.y;
        }

        const int lab = label[row];
        const float4* xr = (const float4*)(x + (size_t)row * DIM);
        const float4* wr = (const float4*)(w + (size_t)lab * DIM);
        float dot = 0.f, nx = 0.f, nw = 0.f;
        #pragma unroll
        for (int q = 0; q < 48; ++q) {
            float4 a = xr[q], b = wr[q];
            dot += a.x * b.x + a.y * b.y + a.z * b.z + a.w * b.w;
            nx  += a.x * a.x + a.y * a.y + a.z * a.z + a.w * a.w;
            nw  += b.x * b.x + b.y * b.y + b.z * b.z + b.w * b.w;
        }
        float cosl    = dot / fmaxf(sqrtf(nx) * sqrtf(nw), 1e-12f);
        float t_plain = S_SCALE * cosl;
        float sine    = sqrtf(fmaxf(0.f, fminf(1.f, 1.f - cosl * cosl)));
        float phi     = cosl * COS_M - sine * SIN_M;
        float modv    = ((cosl - TH_C) > 0.f) ? phi : (cosl - MM_C);
        float t_mod   = S_SCALE * modv;

        float Ladj = L - __expf(t_plain - 30.0f) + __expf(t_mod - 30.0f);
        Ladj = fmaxf(Ladj, 1e-37f);
        float loss = (30.0f + logf(Ladj)) - t_mod;
        float corr = (t_mod > S_SCALE * Mc) ? 1.f : 0.f;

        #pragma unroll
        for (int off = 16; off > 0; off >>= 1) {
            loss += __shfl_xor(loss, off);
            corr += __shfl_xor(corr, off);
        }
        if (t == 0) {
            atomicAdd(&accum[0], loss);
            atomicAdd(&accum[1], corr);
            __threadfence();
            int old = atomicAdd((int*)accum + 2, 1);
            if (old == (int)gridDim.x - 1) {
                float a0 = atomicAdd(&accum[0], 0.0f);
                float a1 = atomicAdd(&accum[1], 0.0f);
                out[0] = a0 * (1.0f / (float)B_ROWS);
                out[1] = a1 * (100.0f / (float)B_ROWS);
            }
        }
    }
}

// ---------------------------------------------------------------------------
extern "C" void kernel_launch(void* const* d_in, const int* in_sizes, int n_in,
                              void* d_out, int out_size, void* d_ws, size_t ws_size,
                              hipStream_t stream)
{
    const float* x     = (const float*)d_in[0];
    const float* w     = (const float*)d_in[1];
    const int*   label = (const int*)d_in[2];
    float* out = (float*)d_out;

    char* ws = (char*)d_ws;
    float* accum = (float*)ws;
    unsigned short* asw = (unsigned short*)(ws + 256);
    const size_t asw_bytes = (size_t)NCHUNKR * ASEG_CH * 16;           // 393216

    const size_t wsw_bytes    = (size_t)NCHUNKC * 24 * 64 * 16;       // 38535168
    const size_t pslot2_bytes = (size_t)NSLOT2 * B_ROWS * 8;          // 1048576
    const size_t need_new = 256 + asw_bytes + wsw_bytes + pslot2_bytes;

    if (ws_size >= need_new) {
        unsigned short* wsw = (unsigned short*)(ws + 256 + asw_bytes);
        float2* pslot2 = (float2*)(ws + 256 + asw_bytes + wsw_bytes);
        pack2_kernel<<<dim3(PACK_GRID), dim3(256), 0, stream>>>(x, w, asw, wsw, accum);
        gemm_stats10_kernel<<<dim3(4 * CSPLIT), dim3(256), 0, stream>>>(asw, wsw, pslot2);
        finalize2_kernel<<<dim3(B_ROWS / 32), dim3(256), 0, stream>>>(
            pslot2, x, w, label, accum, out);
    } else {
        unsigned int* pslot = (unsigned int*)(ws + 256 + asw_bytes);
        prep_kernel<<<dim3(8), dim3(256), 0, stream>>>(x, asw, accum);
        gemm_stats_kernel<<<dim3(NTILE_B), dim3(256), 0, stream>>>(w, asw, pslot);
        finalize_kernel<<<dim3(B_ROWS / 32), dim3(256), 0, stream>>>(
            pslot, x, w, label, accum, out);
    }
}